// Round 7
// baseline (168.486 us; speedup 1.0000x reference)
//
#include <hip/hip_runtime.h>
#include <hip/hip_cooperative_groups.h>
#include <math.h>

namespace cg = cooperative_groups;

#define NH 4    // heads
#define DH 8    // head dim
#define NF 64   // F
#define NT 12   // T
#define NB 2    // batch

// Branchless exact-gelu: x * 0.5 * (1 + erf(x/sqrt(2))).
// erf via Abramowitz-Stegun 7.1.26 (max abs err 1.5e-7), no divergence.
// R0 vs R2/R4 A/B: identical absmax & time vs OCML erff; VALU fully hidden.
__device__ __forceinline__ float gelu_f(float x) {
    const float s = x * 0.70710678118654752440f;
    const float z = __builtin_fabsf(s);
    const float t = __builtin_amdgcn_rcpf(fmaf(0.3275911f, z, 1.0f));
    float p = fmaf(1.061405429f, t, -1.453152027f);
    p = fmaf(p, t, 1.421413741f);
    p = fmaf(p, t, -0.284496736f);
    p = fmaf(p, t, 0.254829592f);
    p *= t;
    const float e = __builtin_amdgcn_exp2f(z * z * -1.44269504088896340736f); // exp(-z^2)
    const float erfa = fmaf(-p, e, 1.0f);                      // erf(|s|)
    const float erfv = __builtin_copysignf(erfa, s);           // erf(s)
    return 0.5f * x * (1.0f + erfv);
}

// Fused cooperative kernel.
// Phase 0: each block streams the adj rows it will later score into its own
//          XCD's L2/L3 (keep-alive via asm so the loads aren't DCE'd).
// Phase 1: qk — one wave per (b,n) row, writes sqT/skT (transposed).
// grid.sync()
// Phase 2: score — block b scores row i=b (grid-stride): reads adj (now
//          L2/L3-resident -> phase 2 is a ~pure-write DRAM stream), loops
//          the 8 (b,h) output streams with register-held adj.
__global__ __launch_bounds__(256, 8) void fused_kernel(
    const float* __restrict__ x, const float* __restrict__ adj,
    const float* __restrict__ w1, const float* __restrict__ W2,
    const float* __restrict__ a,
    float* __restrict__ sqT, float* __restrict__ skT,
    float* __restrict__ out, int N)
{
    const int tid = threadIdx.x;
    const int nq = N >> 2;

    // ---- Phase 0: adj prefetch (rows this block will score) ----
    {
        float keep = 0.f;
        for (int i = blockIdx.x; i < N; i += gridDim.x) {
            const float4* arow = (const float4*)(adj + (long long)i * N);
            for (int q = tid; q < nq; q += 256) {
                float4 p = arow[q];
                keep += p.x;
            }
        }
        asm volatile("" :: "v"(keep));   // keep loads alive (rule #17)
    }

    // ---- Fold W2 with aq/ak -> Wq/Wk in LDS ----
    __shared__ float Wq[NF][NH + 1];
    __shared__ float Wk[NF][NH + 1];
    {
        int f = tid >> 2, h = tid & 3;
        float accq = 0.f, acck = 0.f;
        #pragma unroll
        for (int k = 0; k < DH; ++k) {
            float w = W2[f * (NH * DH) + h * DH + k];
            accq += w * a[k];
            acck += w * a[DH + k];
        }
        Wq[f][h] = accq;
        Wk[f][h] = acck;
    }
    __syncthreads();

    // ---- Phase 1: qk (one wave per (b,n) row, 4 rows per active block) ----
    {
        float w1r[NT];
        #pragma unroll
        for (int i = 0; i < NT; ++i) w1r[i] = w1[i];

        const int wave = tid >> 6;
        const int lane = tid & 63;                  // = f
        const int qkBlocks = (NB * N) >> 2;         // rows/4
        for (int qb = blockIdx.x; qb < qkBlocks; qb += gridDim.x) {
            const long long row = (long long)qb * 4 + wave;   // < NB*N

            const float* xr = x + row * (NF * NT) + (long long)lane * NT;
            float4 v0 = *(const float4*)(xr);
            float4 v1 = *(const float4*)(xr + 4);
            float4 v2 = *(const float4*)(xr + 8);
            float dot = v0.x*w1r[0] + v0.y*w1r[1] + v0.z*w1r[2]  + v0.w*w1r[3]
                      + v1.x*w1r[4] + v1.y*w1r[5] + v1.z*w1r[6]  + v1.w*w1r[7]
                      + v2.x*w1r[8] + v2.y*w1r[9] + v2.z*w1r[10] + v2.w*w1r[11];
            float q = gelu_f(dot);

            float acc[8];
            #pragma unroll
            for (int h = 0; h < NH; ++h) {
                acc[h]     = q * Wq[lane][h];
                acc[4 + h] = q * Wk[lane][h];
            }
            #pragma unroll
            for (int ofs = 32; ofs > 0; ofs >>= 1) {
                #pragma unroll
                for (int i = 0; i < 8; ++i)
                    acc[i] += __shfl_xor(acc[i], ofs, 64);
            }
            if (lane < 8) {
                int h   = lane & 3;
                int isK = lane >> 2;
                int b   = (int)(row / N);
                int n   = (int)(row % N);
                float* dst = isK ? skT : sqT;
                dst[((long long)b * NH + h) * N + n] = acc[lane];
            }
        }
    }

    cg::this_grid().sync();

    // ---- Phase 2: score (block-per-row, grid-stride) ----
    const float aadj = a[2 * DH];
    for (int i = blockIdx.x; i < N; i += gridDim.x) {
        for (int q = tid; q < nq; q += 256) {
            const int j0 = q << 2;
            float4 adj4 = *(const float4*)(adj + (long long)i * N + j0);
            const float a0 = adj4.x * aadj;
            const float a1 = adj4.y * aadj;
            const float a2 = adj4.z * aadj;
            const float a3 = adj4.w * aadj;

            #pragma unroll
            for (int bh = 0; bh < NB * NH; ++bh) {
                const float sq = sqT[(long long)bh * N + i];
                float4 sk4 = *(const float4*)(skT + (long long)bh * N + j0);
                float4 o;
                o.x = gelu_f(sq + sk4.x + a0);
                o.y = gelu_f(sq + sk4.y + a1);
                o.z = gelu_f(sq + sk4.z + a2);
                o.w = gelu_f(sq + sk4.w + a3);
                *(float4*)(out + ((long long)bh * N + i) * N + j0) = o;
            }
        }
    }
}

extern "C" void kernel_launch(void* const* d_in, const int* in_sizes, int n_in,
                              void* d_out, int out_size, void* d_ws, size_t ws_size,
                              hipStream_t stream)
{
    const float* x   = (const float*)d_in[0];
    const float* adj = (const float*)d_in[1];
    const float* w1  = (const float*)d_in[2];
    const float* W2  = (const float*)d_in[3];
    const float* a   = (const float*)d_in[4];
    float* out = (float*)d_out;

    // N from adj (N*N elements); B fixed at 2 per reference setup.
    int N = 1;
    while ((long long)(N + 1) * (N + 1) <= (long long)in_sizes[1]) ++N;

    float* sqT = (float*)d_ws;                 // NB*NH*N floats
    float* skT = sqT + (size_t)NB * NH * N;    // NB*NH*N floats

    // Cooperative grid: want one block per score row (N=2048 = 256 CU x 8),
    // capped by what the device can co-schedule. Grid-stride loops handle any grid.
    int blocksPerCU = 8;
    (void)hipOccupancyMaxActiveBlocksPerMultiprocessor(&blocksPerCU, fused_kernel, 256, 0);
    if (blocksPerCU < 1) blocksPerCU = 1;
    int grid = blocksPerCU * 256;              // 256 CUs on MI355X
    if (grid > N) grid = N;

    void* args[] = { (void*)&x, (void*)&adj, (void*)&w1, (void*)&W2, (void*)&a,
                     (void*)&sqT, (void*)&skT, (void*)&out, (void*)&N };
    hipLaunchCooperativeKernel((const void*)fused_kernel, dim3(grid), dim3(256),
                               args, 0, stream);
}

// Round 8
// 44.134 us; speedup vs baseline: 3.8176x; 3.8176x over previous
//
#include <hip/hip_runtime.h>
#include <math.h>

#define NH 4    // heads
#define DH 8    // head dim
#define NF 64   // F
#define NT 12   // T
#define NB 2    // batch

typedef float vfloat4 __attribute__((ext_vector_type(4)));

// Branchless exact-gelu: x * 0.5 * (1 + erf(x/sqrt(2))).
// erf via Abramowitz-Stegun 7.1.26 (max abs err 1.5e-7), no divergence.
// R0 vs R2/R4 A/B: identical absmax & time vs OCML erff; VALU fully hidden.
__device__ __forceinline__ float gelu_f(float x) {
    const float s = x * 0.70710678118654752440f;
    const float z = __builtin_fabsf(s);
    const float t = __builtin_amdgcn_rcpf(fmaf(0.3275911f, z, 1.0f));
    float p = fmaf(1.061405429f, t, -1.453152027f);
    p = fmaf(p, t, 1.421413741f);
    p = fmaf(p, t, -0.284496736f);
    p = fmaf(p, t, 0.254829592f);
    p *= t;
    const float e = __builtin_amdgcn_exp2f(z * z * -1.44269504088896340736f); // exp(-z^2)
    const float erfa = fmaf(-p, e, 1.0f);                      // erf(|s|)
    const float erfv = __builtin_copysignf(erfa, s);           // erf(s)
    return 0.5f * x * (1.0f + erfv);
}

// One wave (64 lanes) per (b,n) row; lane = f.
// Computes sqT[(b*NH+h)*N + n] and skT[...] (transposed layout for score_kernel).
__global__ __launch_bounds__(256) void qk_kernel(
    const float* __restrict__ x, const float* __restrict__ w1,
    const float* __restrict__ W2, const float* __restrict__ a,
    float* __restrict__ sqT, float* __restrict__ skT, int N)
{
    __shared__ float Wq[NF][NH + 1];
    __shared__ float Wk[NF][NH + 1];
    const int t = threadIdx.x;

    // Fold W2 (64x32) with aq/ak (8 each) -> Wq/Wk (64x4), once per block.
    {
        int f = t >> 2, h = t & 3;
        float accq = 0.f, acck = 0.f;
        #pragma unroll
        for (int k = 0; k < DH; ++k) {
            float w = W2[f * (NH * DH) + h * DH + k];
            accq += w * a[k];
            acck += w * a[DH + k];
        }
        Wq[f][h] = accq;
        Wk[f][h] = acck;
    }
    __syncthreads();

    float w1r[NT];
    #pragma unroll
    for (int i = 0; i < NT; ++i) w1r[i] = w1[i];

    const int wave = t >> 6;
    const int lane = t & 63;                      // = f
    const long long row = (long long)blockIdx.x * 4 + wave;   // in [0, NB*N)
    if (row >= (long long)NB * N) return;

    const float* xr = x + row * (NF * NT) + (long long)lane * NT;
    float4 v0 = *(const float4*)(xr);
    float4 v1 = *(const float4*)(xr + 4);
    float4 v2 = *(const float4*)(xr + 8);
    float dot = v0.x*w1r[0] + v0.y*w1r[1] + v0.z*w1r[2]  + v0.w*w1r[3]
              + v1.x*w1r[4] + v1.y*w1r[5] + v1.z*w1r[6]  + v1.w*w1r[7]
              + v2.x*w1r[8] + v2.y*w1r[9] + v2.z*w1r[10] + v2.w*w1r[11];
    float q = gelu_f(dot);

    float acc[8];
    #pragma unroll
    for (int h = 0; h < NH; ++h) {
        acc[h]     = q * Wq[lane][h];
        acc[4 + h] = q * Wk[lane][h];
    }
    #pragma unroll
    for (int ofs = 32; ofs > 0; ofs >>= 1) {
        #pragma unroll
        for (int i = 0; i < 8; ++i)
            acc[i] += __shfl_xor(acc[i], ofs, 64);
    }
    if (lane < 8) {
        int h   = lane & 3;
        int isK = lane >> 2;
        int b   = (int)(row / N);
        int n   = (int)(row % N);
        float* dst = isK ? skT : sqT;
        dst[((long long)b * NH + h) * N + n] = acc[lane];
    }
}

// R8: exact R4 structure (best, 35.0us) with ONE change: adj loads are
// nontemporal. adj is use-once streaming data (16.8MB); NT keeps it from
// allocating in L2, leaving L2 as a pure write-combining buffer for the
// 134MB output stream. (nt STORES hurt -1.5us in R2 — the converse.)
__global__ __launch_bounds__(256) void score_kernel(
    const float* __restrict__ adj, const float* __restrict__ sqT,
    const float* __restrict__ skT, const float* __restrict__ a,
    float* __restrict__ out, int N)
{
    const float aadj = a[2 * DH];
    const int nq = N >> 2;                         // j-quads per row
    long long tid = (long long)blockIdx.x * blockDim.x + threadIdx.x;
    if (tid >= (long long)N * nq) return;
    const int i  = (int)(tid / nq);
    const int j0 = (int)(tid % nq) << 2;

    vfloat4 adj4 = __builtin_nontemporal_load((const vfloat4*)(adj + (long long)i * N + j0));
    const float a0 = adj4.x * aadj;
    const float a1 = adj4.y * aadj;
    const float a2 = adj4.z * aadj;
    const float a3 = adj4.w * aadj;

    #pragma unroll
    for (int bh = 0; bh < NB * NH; ++bh) {
        const float sq = sqT[(long long)bh * N + i];
        float4 sk4 = *(const float4*)(skT + (long long)bh * N + j0);
        float4 o;
        o.x = gelu_f(sq + sk4.x + a0);
        o.y = gelu_f(sq + sk4.y + a1);
        o.z = gelu_f(sq + sk4.z + a2);
        o.w = gelu_f(sq + sk4.w + a3);
        *(float4*)(out + ((long long)bh * N + i) * N + j0) = o;
    }
}

extern "C" void kernel_launch(void* const* d_in, const int* in_sizes, int n_in,
                              void* d_out, int out_size, void* d_ws, size_t ws_size,
                              hipStream_t stream)
{
    const float* x   = (const float*)d_in[0];
    const float* adj = (const float*)d_in[1];
    const float* w1  = (const float*)d_in[2];
    const float* W2  = (const float*)d_in[3];
    const float* a   = (const float*)d_in[4];
    float* out = (float*)d_out;

    // N from adj (N*N elements); B fixed at 2 per reference setup.
    int N = 1;
    while ((long long)(N + 1) * (N + 1) <= (long long)in_sizes[1]) ++N;

    float* sqT = (float*)d_ws;                 // NB*NH*N floats
    float* skT = sqT + (size_t)NB * NH * N;    // NB*NH*N floats

    const int rows = NB * N;                   // one wave per row, 4 waves/block
    qk_kernel<<<(rows + 3) / 4, 256, 0, stream>>>(x, w1, W2, a, sqT, skT, N);

    const long long total = (long long)N * (N >> 2);
    score_kernel<<<(int)((total + 255) / 256), 256, 0, stream>>>(adj, sqT, skT, a, out, N);
}

// Round 9
// 34.796 us; speedup vs baseline: 4.8422x; 1.2684x over previous
//
#include <hip/hip_runtime.h>
#include <math.h>

#define NH 4    // heads
#define DH 8    // head dim
#define NF 64   // F
#define NT 12   // T
#define NB 2    // batch
#define IT 4    // i-rows tiled per score block (skT reuse factor)

// Branchless exact-gelu: x * 0.5 * (1 + erf(x/sqrt(2))).
// erf via Abramowitz-Stegun 7.1.26 (max abs err 1.5e-7), no divergence.
// R0 vs R2/R4 A/B: identical absmax & time vs OCML erff; VALU fully hidden.
__device__ __forceinline__ float gelu_f(float x) {
    const float s = x * 0.70710678118654752440f;
    const float z = __builtin_fabsf(s);
    const float t = __builtin_amdgcn_rcpf(fmaf(0.3275911f, z, 1.0f));
    float p = fmaf(1.061405429f, t, -1.453152027f);
    p = fmaf(p, t, 1.421413741f);
    p = fmaf(p, t, -0.284496736f);
    p = fmaf(p, t, 0.254829592f);
    p *= t;
    const float e = __builtin_amdgcn_exp2f(z * z * -1.44269504088896340736f); // exp(-z^2)
    const float erfa = fmaf(-p, e, 1.0f);                      // erf(|s|)
    const float erfv = __builtin_copysignf(erfa, s);           // erf(s)
    return 0.5f * x * (1.0f + erfv);
}

// One wave (64 lanes) per (b,n) row; lane = f.
// Computes sqT[(b*NH+h)*N + n] and skT[...] (transposed layout for score_kernel).
__global__ __launch_bounds__(256) void qk_kernel(
    const float* __restrict__ x, const float* __restrict__ w1,
    const float* __restrict__ W2, const float* __restrict__ a,
    float* __restrict__ sqT, float* __restrict__ skT, int N)
{
    __shared__ float Wq[NF][NH + 1];
    __shared__ float Wk[NF][NH + 1];
    const int t = threadIdx.x;

    // Fold W2 (64x32) with aq/ak (8 each) -> Wq/Wk (64x4), once per block.
    {
        int f = t >> 2, h = t & 3;
        float accq = 0.f, acck = 0.f;
        #pragma unroll
        for (int k = 0; k < DH; ++k) {
            float w = W2[f * (NH * DH) + h * DH + k];
            accq += w * a[k];
            acck += w * a[DH + k];
        }
        Wq[f][h] = accq;
        Wk[f][h] = acck;
    }
    __syncthreads();

    float w1r[NT];
    #pragma unroll
    for (int i = 0; i < NT; ++i) w1r[i] = w1[i];

    const int wave = t >> 6;
    const int lane = t & 63;                      // = f
    const long long row = (long long)blockIdx.x * 4 + wave;   // in [0, NB*N)
    if (row >= (long long)NB * N) return;

    const float* xr = x + row * (NF * NT) + (long long)lane * NT;
    float4 v0 = *(const float4*)(xr);
    float4 v1 = *(const float4*)(xr + 4);
    float4 v2 = *(const float4*)(xr + 8);
    float dot = v0.x*w1r[0] + v0.y*w1r[1] + v0.z*w1r[2]  + v0.w*w1r[3]
              + v1.x*w1r[4] + v1.y*w1r[5] + v1.z*w1r[6]  + v1.w*w1r[7]
              + v2.x*w1r[8] + v2.y*w1r[9] + v2.z*w1r[10] + v2.w*w1r[11];
    float q = gelu_f(dot);

    float acc[8];
    #pragma unroll
    for (int h = 0; h < NH; ++h) {
        acc[h]     = q * Wq[lane][h];
        acc[4 + h] = q * Wk[lane][h];
    }
    #pragma unroll
    for (int ofs = 32; ofs > 0; ofs >>= 1) {
        #pragma unroll
        for (int i = 0; i < 8; ++i)
            acc[i] += __shfl_xor(acc[i], ofs, 64);
    }
    if (lane < 8) {
        int h   = lane & 3;
        int isK = lane >> 2;
        int b   = (int)(row / N);
        int n   = (int)(row % N);
        float* dst = isK ? skT : sqT;
        dst[((long long)b * NH + h) * N + n] = acc[lane];
    }
}

// R9: R4 structure + i-tiling. Each block owns a 256-quad j-window and IT=4
// consecutive output rows. Each thread register-holds its 8 skT quads and
// reuses them for all IT rows -> skT L2 read traffic drops IT x (134->33MB).
// adj/out HBM traffic and the per-wave 1KB-burst store pattern are identical
// to R4 (35.0us champion).
__global__ __launch_bounds__(256) void score_kernel_tiled(
    const float* __restrict__ adj, const float* __restrict__ sqT,
    const float* __restrict__ skT, const float* __restrict__ a,
    float* __restrict__ out, int N)
{
    const float aadj = a[2 * DH];
    const int nq  = N >> 2;
    const int wpr = nq >> 8;                        // 256-quad windows per row
    const int ig = blockIdx.x / wpr;                // i-group
    const int w  = blockIdx.x - ig * wpr;           // window within row
    const int i0 = ig * IT;
    const int j0 = ((w << 8) + threadIdx.x) << 2;   // absolute column

    // Register-stage this thread's skT quad for each bh (8 x float4 = 32 VGPR).
    float4 sk[NB * NH];
    #pragma unroll
    for (int bh = 0; bh < NB * NH; ++bh)
        sk[bh] = *(const float4*)(skT + (long long)bh * N + j0);

    #pragma unroll
    for (int ii = 0; ii < IT; ++ii) {
        const int i = i0 + ii;
        float4 adj4 = *(const float4*)(adj + (long long)i * N + j0);
        const float a0 = adj4.x * aadj;
        const float a1 = adj4.y * aadj;
        const float a2 = adj4.z * aadj;
        const float a3 = adj4.w * aadj;

        #pragma unroll
        for (int bh = 0; bh < NB * NH; ++bh) {
            const float sq = sqT[(long long)bh * N + i];
            float4 o;
            o.x = gelu_f(sq + sk[bh].x + a0);
            o.y = gelu_f(sq + sk[bh].y + a1);
            o.z = gelu_f(sq + sk[bh].z + a2);
            o.w = gelu_f(sq + sk[bh].w + a3);
            *(float4*)(out + ((long long)bh * N + i) * N + j0) = o;
        }
    }
}

// Fallback (exact R4 kernel) for shapes where the tiled mapping doesn't divide.
__global__ __launch_bounds__(256) void score_kernel_flat(
    const float* __restrict__ adj, const float* __restrict__ sqT,
    const float* __restrict__ skT, const float* __restrict__ a,
    float* __restrict__ out, int N)
{
    const float aadj = a[2 * DH];
    const int nq = N >> 2;
    long long tid = (long long)blockIdx.x * blockDim.x + threadIdx.x;
    if (tid >= (long long)N * nq) return;
    const int i  = (int)(tid / nq);
    const int j0 = (int)(tid % nq) << 2;

    float4 adj4 = *(const float4*)(adj + (long long)i * N + j0);
    const float a0 = adj4.x * aadj;
    const float a1 = adj4.y * aadj;
    const float a2 = adj4.z * aadj;
    const float a3 = adj4.w * aadj;

    #pragma unroll
    for (int bh = 0; bh < NB * NH; ++bh) {
        const float sq = sqT[(long long)bh * N + i];
        float4 sk4 = *(const float4*)(skT + (long long)bh * N + j0);
        float4 o;
        o.x = gelu_f(sq + sk4.x + a0);
        o.y = gelu_f(sq + sk4.y + a1);
        o.z = gelu_f(sq + sk4.z + a2);
        o.w = gelu_f(sq + sk4.w + a3);
        *(float4*)(out + ((long long)bh * N + i) * N + j0) = o;
    }
}

extern "C" void kernel_launch(void* const* d_in, const int* in_sizes, int n_in,
                              void* d_out, int out_size, void* d_ws, size_t ws_size,
                              hipStream_t stream)
{
    const float* x   = (const float*)d_in[0];
    const float* adj = (const float*)d_in[1];
    const float* w1  = (const float*)d_in[2];
    const float* W2  = (const float*)d_in[3];
    const float* a   = (const float*)d_in[4];
    float* out = (float*)d_out;

    // N from adj (N*N elements); B fixed at 2 per reference setup.
    int N = 1;
    while ((long long)(N + 1) * (N + 1) <= (long long)in_sizes[1]) ++N;

    float* sqT = (float*)d_ws;                 // NB*NH*N floats
    float* skT = sqT + (size_t)NB * NH * N;    // NB*NH*N floats

    const int rows = NB * N;                   // one wave per row, 4 waves/block
    qk_kernel<<<(rows + 3) / 4, 256, 0, stream>>>(x, w1, W2, a, sqT, skT, N);

    const int nq = N >> 2;
    if ((nq & 255) == 0 && (N % IT) == 0) {
        const int wpr = nq >> 8;
        const int blocks = (N / IT) * wpr;     // 1024 at N=2048
        score_kernel_tiled<<<blocks, 256, 0, stream>>>(adj, sqT, skT, a, out, N);
    } else {
        const long long total = (long long)N * nq;
        score_kernel_flat<<<(int)((total + 255) / 256), 256, 0, stream>>>(adj, sqT, skT, a, out, N);
    }
}